// Round 1
// 190.592 us; speedup vs baseline: 1.0525x; 1.0525x over previous
//
#include <hip/hip_runtime.h>

#define HIDDEN 64
#define HALFD  32
#define VOCAB  64
#define BATCH  256
#define SEQLEN 2048

#define RLF(v, sl) __int_as_float(__builtin_amdgcn_readlane(__float_as_int(v), (sl)))
#define RLI(v, sl) __builtin_amdgcn_readlane((v), (sl))
#define GIX(j,m) (((j)==0?0:(j)==1?7:(j)==2?13:(j)==3?18:(j)==4?22:(j)==5?25:27) + (m) - (j) - 1)
#define OM(m) (((m)*((m)+1))>>1)

// ---------------------------------------------------------------------------
// Kernel 1: per-token vocab tables.
//   ws[0    ..2047]  ks_voc [64][32]  (normalized hs)
//   ws[2048 ..4095]  ke_voc [64][32]  (normalized he)
//   ws[4096 ..6143]  vs_voc [64][32]  (raw hs)
//   ws[6144 ..8191]  ve_voc [64][32]  (raw he)
//   ws[8192 ..16383] Gs,Ge [2][64][64]
// ---------------------------------------------------------------------------
__global__ __launch_bounds__(64) void vocab_kernel(
    const float* __restrict__ embed, const float* __restrict__ W1, const float* __restrict__ b1,
    const float* __restrict__ W2, const float* __restrict__ b2,
    const float* __restrict__ ln_g, const float* __restrict__ ln_b,
    const float* __restrict__ Ws, const float* __restrict__ bs,
    const float* __restrict__ We, const float* __restrict__ be,
    float* __restrict__ ws)
{
    const int v = blockIdx.x;
    const int tid = threadIdx.x;

    __shared__ float e_s[64];
    __shared__ float a1_s[128];
    __shared__ float h_s[64];

    e_s[tid] = embed[v * 64 + tid];
    __syncthreads();

    // layer 1: 4 partial accumulators break the 64-deep serial FMA chain
    float p0 = b1[tid], p1 = 0.f, p2 = 0.f, p3 = 0.f;
    float q0 = b1[tid + 64], q1 = 0.f, q2 = 0.f, q3 = 0.f;
    #pragma unroll
    for (int m = 0; m < 64; m += 4) {
        p0 = fmaf(e_s[m],   W1[tid * 64 + m],     p0);
        p1 = fmaf(e_s[m+1], W1[tid * 64 + m + 1], p1);
        p2 = fmaf(e_s[m+2], W1[tid * 64 + m + 2], p2);
        p3 = fmaf(e_s[m+3], W1[tid * 64 + m + 3], p3);
        q0 = fmaf(e_s[m],   W1[(tid + 64) * 64 + m],     q0);
        q1 = fmaf(e_s[m+1], W1[(tid + 64) * 64 + m + 1], q1);
        q2 = fmaf(e_s[m+2], W1[(tid + 64) * 64 + m + 2], q2);
        q3 = fmaf(e_s[m+3], W1[(tid + 64) * 64 + m + 3], q3);
    }
    a1_s[tid]      = fmaxf((p0 + p1) + (p2 + p3), 0.0f);
    a1_s[tid + 64] = fmaxf((q0 + q1) + (q2 + q3), 0.0f);
    __syncthreads();

    float f0 = b2[tid], f1 = 0.f, f2 = 0.f, f3 = 0.f;
    #pragma unroll
    for (int m = 0; m < 128; m += 4) {
        f0 = fmaf(a1_s[m],   W2[tid * 128 + m],     f0);
        f1 = fmaf(a1_s[m+1], W2[tid * 128 + m + 1], f1);
        f2 = fmaf(a1_s[m+2], W2[tid * 128 + m + 2], f2);
        f3 = fmaf(a1_s[m+3], W2[tid * 128 + m + 3], f3);
    }
    float x = e_s[tid] + ((f0 + f1) + (f2 + f3));

    float s = x, s2 = x * x;
    #pragma unroll
    for (int off = 32; off >= 1; off >>= 1) {
        s  += __shfl_xor(s,  off, 64);
        s2 += __shfl_xor(s2, off, 64);
    }
    float mu  = s * (1.0f / 64.0f);
    float var = s2 * (1.0f / 64.0f) - mu * mu;
    float hval = (x - mu) * rsqrtf(var + 1e-5f) * ln_g[tid] + ln_b[tid];
    h_s[tid] = hval;
    __syncthreads();

    const int j = tid & 31;
    const bool is_s = tid < 32;
    const float* W = is_s ? Ws : We;
    float c0 = is_s ? bs[j] : be[j];
    float c1 = 0.f, c2 = 0.f, c3 = 0.f;
    #pragma unroll
    for (int m = 0; m < 64; m += 4) {
        c0 = fmaf(h_s[m],   W[j * 64 + m],     c0);
        c1 = fmaf(h_s[m+1], W[j * 64 + m + 1], c1);
        c2 = fmaf(h_s[m+2], W[j * 64 + m + 2], c2);
        c3 = fmaf(h_s[m+3], W[j * 64 + m + 3], c3);
    }
    float acc = (c0 + c1) + (c2 + c3);

    float n2 = acc * acc;
    #pragma unroll
    for (int off = 16; off >= 1; off >>= 1) n2 += __shfl_xor(n2, off, 64);
    float norm = sqrtf(n2);
    float kn = acc / fmaxf(norm, 1e-12f);

    const int base = v * 32 + j;
    if (is_s) { ws[base]        = kn; ws[4096 + base] = acc; }
    else      { ws[2048 + base] = kn; ws[6144 + base] = acc; }
}

// ---------------------------------------------------------------------------
// Kernel 1b: Gram tables G_w[a][b] = k_w[a].k_w[b], [64][64] in ws.
// 8 blocks (branch x 4 row-segments); k_s padded to 33 to kill the 16-way
// LDS bank conflict of the unpadded [64][32] layout.
// ---------------------------------------------------------------------------
__global__ __launch_bounds__(256) void gram_kernel(float* __restrict__ ws)
{
    const int w   = blockIdx.x & 1;
    const int seg = blockIdx.x >> 1;          // 0..3
    const int tid = threadIdx.x;
    __shared__ float k_s[64][33];
    const float* kb = ws + w * 2048;
    for (int i = tid; i < 2048; i += 256) k_s[i >> 5][i & 31] = kb[i];
    __syncthreads();
    const int a  = seg * 16 + (tid >> 4);     // row
    const int b0 = (tid & 15) << 2;           // 4 cols per thread
    float* Gw = ws + 8192 + w * 4096 + a * 64;
    #pragma unroll
    for (int bb = 0; bb < 4; ++bb) {
        const int bcol = b0 + bb;
        float acc0 = 0.f, acc1 = 0.f;
        #pragma unroll
        for (int m = 0; m < 32; m += 2) {
            acc0 = fmaf(k_s[a][m],     k_s[bcol][m],     acc0);
            acc1 = fmaf(k_s[a][m + 1], k_s[bcol][m + 1], acc1);
        }
        Gw[bcol] = acc0 + acc1;
    }
}

// chunk-8 solve-matrix build: s = W t with f folded (verbatim R9 math)
static __device__ __forceinline__ void build_wpack(
    const int* tj, float fb, float invL, bool is_e, bool is_last, float* Wp,
    const float* __restrict__ Gg)
{
    float f[8];
    #pragma unroll
    for (int j = 0; j < 8; ++j) f[j] = is_e ? (fb + (float)j * invL) : 1.0f;
    if (is_last) f[7] = 0.0f;     // position 2047 is the query, not a write

    float g[28];
    #pragma unroll
    for (int j = 0; j < 7; ++j)
        #pragma unroll
        for (int m = j + 1; m < 8; ++m) g[GIX(j, m)] = Gg[tj[j] * 64 + tj[m]];

    #pragma unroll
    for (int m = 0; m < 8; ++m) {
        float col[8];
        col[m] = f[m];
        #pragma unroll
        for (int j = 6; j >= 0; --j) {
            if (j < m) {
                float acc = 0.0f;
                #pragma unroll
                for (int p = 1; p < 8; ++p)
                    if (p > j && p <= m) acc = fmaf(g[GIX(j, p)], col[p], acc);
                col[j] = -f[j] * acc;
            }
        }
        #pragma unroll
        for (int j = 0; j < 8; ++j)
            if (j <= m) Wp[OM(m) + j] = col[j];
    }
}

struct Chunk {
    int   tokv;      // lane-vector: tok[c*8 + (lane&7)]
    int   tk[8];     // uniform tokens of this chunk (SGPR via v_readlane)
    float grow[8];   // G[tok_j][lane]  (VMEM-prefetched one body ahead)
    float R[8];      // per-lane W row: lane l7=i holds R_i[m]=Wp[OM(m)+i] (m>=i)
    float braw;      // corrected-gather input: shfl(u_{c+1}, tok_c), 2-body slack
    float bp[8];     // correction Gram block: G[tk_{c+1,j}][tk_{c,l7}], 1-body slack
};

// ---------------------------------------------------------------------------
// Kernel 2 (R17): Gram-space backward adjoint sweep, chunk-8, with
// (a) row-distributed s: lane l7=i computes only s_i from its LDS-held W-row
//     (replaces the 43-VALU lane-uniform triangular tree with 12 VALU +
//      2 ds_read_b128), then 8 readlanes re-broadcast s;
// (b) corrected-gather pipeline: braw'_c = shfl(u_{c+1}, tok_c) issued TWO
//     bodies early (before chunk c+1's update), spine reconstructs
//     t_c = braw'_c - sum_j bp_c[j]*s_{c+1,j}  (exact linear identity, since
//     u_c = u_{c+1} - G_{c+1}^T s_{c+1}).  The ds_bpermute latency and the
//     whole u-update move OFF the spine with >= 1 full body of slack.
// Spine per body: s_prev -> 4-deep corr FMA tree -> 8 readlane -> 4-deep
// row FMA tree -> 8 readlane -> s_new.  Everything else is filler.
// W rows in LDS [2][256][8][8] (128 KB), row slot XOR-swizzled by (c&7) so
// prologue scatter-writes don't serialize 64-way; body reads stay 2-way.
// ---------------------------------------------------------------------------
__global__ __launch_bounds__(128) void scan_kernel(
    const int* __restrict__ seq, const float* __restrict__ ws,
    const float* __restrict__ Wrp, const float* __restrict__ brp,
    const float* __restrict__ Wo, const float* __restrict__ bo,
    float* __restrict__ out)
{
    const int b    = blockIdx.x;
    const int tid  = threadIdx.x;        // 0..127
    const int w    = tid >> 6;           // wave: 0 = s-branch, 1 = e-branch
    const int lane = tid & 63;
    const int l7   = lane & 7;
    const bool is_e = (w == 1);

    __shared__ __align__(16) float Wlds[2][256][8][8];   // 128 KB
    __shared__ __align__(16) int   toklds[SEQLEN];       // 8 KB (prologue only)
    __shared__ float wacc_s[2][64];
    __shared__ float r_s[64];
    __shared__ float t1_s[64];

    const float* Gg = ws + 8192 + w * 4096;
    const int*   sq = seq + b * SEQLEN;

    // ---- stage token sequence (for the W-build prologue) ----
    {
        const int4* sq4 = (const int4*)sq;
        int4* tl = (int4*)toklds;
        #pragma unroll
        for (int i = 0; i < 4; ++i) tl[tid + i * 128] = sq4[tid + i * 128];
    }
    __syncthreads();

    // ---- precompute W row-tables: lanes parallel over chunks (4 per lane) ----
    {
        const float invL = 1.0f / (float)SEQLEN;
        #pragma unroll
        for (int qq = 0; qq < 4; ++qq) {
            const int c = lane + (qq << 6);
            int tj[8];
            #pragma unroll
            for (int j = 0; j < 8; ++j) tj[j] = toklds[c * 8 + j];
            float Wp[36];
            build_wpack(tj, (float)(8 * c + 1) * invL, invL, is_e, c == 255, Wp, Gg);
            const int cx = c & 7;
            #pragma unroll
            for (int i = 0; i < 8; ++i) {
                float r[8];
                #pragma unroll
                for (int m = 0; m < 8; ++m) r[m] = (m >= i) ? Wp[OM(m) + i] : 0.0f;
                float4* dst = (float4*)&Wlds[w][c][i ^ cx][0];
                dst[0] = make_float4(r[0], r[1], r[2], r[3]);
                dst[1] = make_float4(r[4], r[5], r[6], r[7]);
            }
        }
    }
    __syncthreads();

    // ---- serial backward sweep ----
    Chunk A, B;
    float u, wacc0 = 0.0f, wacc1 = 0.0f;
    float sp0, sp1, sp2, sp3, sp4, sp5, sp6, sp7;

    // prologue: chunk 255 fully; chunk 254 tokens + braw + bp; chunk 253 tokens
    A.tokv = sq[2040 + l7];
    B.tokv = sq[2032 + l7];
    int tv2 = sq[2024 + l7];
    #pragma unroll
    for (int j = 0; j < 8; ++j) A.tk[j] = RLI(A.tokv, j);
    #pragma unroll
    for (int j = 0; j < 8; ++j) A.grow[j] = Gg[A.tk[j] * 64 + lane];
    {
        const float4* rp = (const float4*)&Wlds[w][255][l7 ^ 7][0];
        float4 lo = rp[0], hi = rp[1];
        A.R[0] = lo.x; A.R[1] = lo.y; A.R[2] = lo.z; A.R[3] = lo.w;
        A.R[4] = hi.x; A.R[5] = hi.y; A.R[6] = hi.z; A.R[7] = hi.w;
    }
    u = Gg[A.tk[7] * 64 + lane];           // query token = position 2047
    A.braw = __shfl(u, A.tokv, 64);        // t_255 raw (corr = 0)
    B.braw = __shfl(u, B.tokv, 64);        // braw'_254 = shfl(u_255, tok_254)
    #pragma unroll
    for (int j = 0; j < 8; ++j) {
        A.bp[j] = 0.0f;
        B.bp[j] = __shfl(A.grow[j], B.tokv, 64);   // G[tk255_j][tk254_l7]
    }
    sp0 = sp1 = sp2 = sp3 = sp4 = sp5 = sp6 = sp7 = 0.0f;

    auto body = [&](Chunk& cur, Chunk& nxt, int c) {
        const int cm1 = (c > 0) ? c - 1 : 0;
        const int cm3 = (c > 2) ? c - 3 : 0;

        // ---- spine head: corrected gather  t = braw' - bp . s_prev ----
        float c01 = fmaf(cur.bp[1], sp1, cur.bp[0] * sp0);
        float c23 = fmaf(cur.bp[3], sp3, cur.bp[2] * sp2);
        float c45 = fmaf(cur.bp[5], sp5, cur.bp[4] * sp4);
        float c67 = fmaf(cur.bp[7], sp7, cur.bp[6] * sp6);
        float tl = cur.braw - ((c01 + c23) + (c45 + c67));
        float t0 = RLF(tl, 0), t1 = RLF(tl, 1), t2 = RLF(tl, 2), t3 = RLF(tl, 3);
        float t4 = RLF(tl, 4), t5 = RLF(tl, 5), t6 = RLF(tl, 6), t7 = RLF(tl, 7);

        // ---- prefetch chunk c-1 into nxt (all off-spine filler) ----
        #pragma unroll
        for (int j = 0; j < 8; ++j) nxt.tk[j] = RLI(nxt.tokv, j);
        #pragma unroll
        for (int j = 0; j < 8; ++j) nxt.grow[j] = Gg[nxt.tk[j] * 64 + lane];
        {
            const float4* rp = (const float4*)&Wlds[w][cm1][l7 ^ (cm1 & 7)][0];
            float4 lo = rp[0], hi = rp[1];
            nxt.R[0] = lo.x; nxt.R[1] = lo.y; nxt.R[2] = lo.z; nxt.R[3] = lo.w;
            nxt.R[4] = hi.x; nxt.R[5] = hi.y; nxt.R[6] = hi.z; nxt.R[7] = hi.w;
        }
        int tv3 = sq[cm3 * 8 + l7];          // tokens of chunk c-3 (per-lane VMEM)

        // ---- spine: distributed s  (lane l7=i computes s_i) ----
        const float* R = cur.R;
        float a0 = fmaf(R[1], t1, R[0] * t0);
        float a1 = fmaf(R[3], t3, R[2] * t2);
        float a2 = fmaf(R[5], t5, R[4] * t4);
        float a3 = fmaf(R[7], t7, R[6] * t6);
        float sd = (a0 + a1) + (a2 + a3);
        float s0 = RLF(sd, 0), s1 = RLF(sd, 1), s2 = RLF(sd, 2), s3 = RLF(sd, 3);
        float s4 = RLF(sd, 4), s5 = RLF(sd, 5), s6 = RLF(sd, 6), s7 = RLF(sd, 7);

        // ---- u update (off-spine), then issue braw for chunk c-2 (2-body
        //      slack) and bp for chunk c-1 (1-body slack) ----
        float dA = fmaf(cur.grow[0], s0, fmaf(cur.grow[1], s1, fmaf(cur.grow[2], s2, cur.grow[3] * s3)));
        float dB = fmaf(cur.grow[4], s4, fmaf(cur.grow[5], s5, fmaf(cur.grow[6], s6, cur.grow[7] * s7)));
        u -= (dA + dB);
        cur.braw = __shfl(u, tv2, 64);               // braw'_{c-2} = shfl(u_{c-1}, tok_{c-2})
        #pragma unroll
        for (int j = 0; j < 8; ++j)
            nxt.bp[j] = __shfl(cur.grow[j], nxt.tokv, 64);   // G[tk_{c,j}][tk_{c-1,l7}]

        // ---- wacc[tok_j] += s_j  (lane = token; off-spine, 2 partials) ----
        wacc0 += (lane == cur.tk[0]) ? s0 : 0.0f;
        wacc1 += (lane == cur.tk[1]) ? s1 : 0.0f;
        wacc0 += (lane == cur.tk[2]) ? s2 : 0.0f;
        wacc1 += (lane == cur.tk[3]) ? s3 : 0.0f;
        wacc0 += (lane == cur.tk[4]) ? s4 : 0.0f;
        wacc1 += (lane == cur.tk[5]) ? s5 : 0.0f;
        wacc0 += (lane == cur.tk[6]) ? s6 : 0.0f;
        wacc1 += (lane == cur.tk[7]) ? s7 : 0.0f;

        // ---- rotate pipeline registers ----
        cur.tokv = tv2; tv2 = tv3;
        sp0 = s0; sp1 = s1; sp2 = s2; sp3 = s3;
        sp4 = s4; sp5 = s5; sp6 = s6; sp7 = s7;
    };

    for (int c = 255; c >= 1; c -= 2) {
        body(A, B, c);
        body(B, A, c - 1);
    }

    wacc_s[w][lane] = wacc0 + wacc1;
    __syncthreads();

    // r[w2][rho] = sum_tok wacc[w2][tok] * v[w2][tok][rho]  (v from global ws)
    if (tid < 64) {
        const int w2  = tid >> 5;
        const int rho = tid & 31;
        const float* vv = ws + 4096 + w2 * 2048;
        const float* wa = &wacc_s[w2][0];
        float acc = 0.0f;
        #pragma unroll 8
        for (int tok = 0; tok < 64; ++tok) acc = fmaf(wa[tok], vv[tok * 32 + rho], acc);
        r_s[tid] = acc;
    }
    __syncthreads();

    // out = (r @ Wrp.T + brp) @ Wo.T + bo
    if (tid < 64) {
        float acc = brp[tid];
        #pragma unroll 8
        for (int m = 0; m < 64; ++m) acc = fmaf(Wrp[tid * 64 + m], r_s[m], acc);
        t1_s[tid] = acc;
    }
    __syncthreads();
    if (tid < 64) {
        float acc = bo[tid];
        #pragma unroll 8
        for (int m = 0; m < 64; ++m) acc = fmaf(Wo[tid * 64 + m], t1_s[m], acc);
        out[b * 64 + tid] = acc;
    }
}

extern "C" void kernel_launch(void* const* d_in, const int* in_sizes, int n_in,
                              void* d_out, int out_size, void* d_ws, size_t ws_size,
                              hipStream_t stream)
{
    const int*   seq   = (const int*)  d_in[0];
    const float* embed = (const float*)d_in[1];
    const float* W1    = (const float*)d_in[2];
    const float* b1    = (const float*)d_in[3];
    const float* W2    = (const float*)d_in[4];
    const float* b2    = (const float*)d_in[5];
    const float* ln_g  = (const float*)d_in[6];
    const float* ln_b  = (const float*)d_in[7];
    const float* Ws    = (const float*)d_in[8];
    const float* bs    = (const float*)d_in[9];
    const float* We    = (const float*)d_in[10];
    const float* be    = (const float*)d_in[11];
    const float* Wrp   = (const float*)d_in[12];
    const float* brp   = (const float*)d_in[13];
    const float* Wo    = (const float*)d_in[14];
    const float* bo    = (const float*)d_in[15];
    float* ws  = (float*)d_ws;
    float* out = (float*)d_out;

    hipLaunchKernelGGL(vocab_kernel, dim3(VOCAB), dim3(64), 0, stream,
                       embed, W1, b1, W2, b2, ln_g, ln_b, Ws, bs, We, be, ws);
    hipLaunchKernelGGL(gram_kernel, dim3(8), dim3(256), 0, stream, ws);
    hipLaunchKernelGGL(scan_kernel, dim3(BATCH), dim3(128), 0, stream,
                       seq, ws, Wrp, brp, Wo, bo, out);
}